// Round 13
// baseline (113.781 us; speedup 1.0000x reference)
//
#include <hip/hip_runtime.h>
#include <stdint.h>

#define BB   32
#define CC1  256
#define HH   56
#define WW   56
#define PH   57          // padded (top/left zero row+col)
#define OHH  28
#define OWW  28
#define NPIX (OHH*OWW)   // 784
#define CC2  512
#define EPSV 1e-5f

static __device__ __forceinline__ int popc64(uint64_t v) {
    return __builtin_popcountll(v);
}
static __device__ __forceinline__ unsigned short f2bf(float f) {
    uint32_t u = __float_as_uint(f);
    u += 0x7FFFu + ((u >> 16) & 1u);          // RNE
    return (unsigned short)(u >> 16);
}
static __device__ __forceinline__ float bf2f(unsigned short u) {
    return __uint_as_float(((uint32_t)u) << 16);
}

// ---------- binx + ALL weight prep in one dispatch (exact R11 winner) ----------
__global__ __launch_bounds__(256) void k_binx(const float* __restrict__ x,
                                              const float* __restrict__ w3,
                                              const float* __restrict__ w1,
                                              const float* __restrict__ g3,
                                              const float* __restrict__ b3,
                                              const float* __restrict__ m3,
                                              const float* __restrict__ v3,
                                              const float* __restrict__ g1,
                                              const float* __restrict__ b1,
                                              const float* __restrict__ m1,
                                              const float* __restrict__ v1,
                                              uint64_t* __restrict__ xbp,
                                              uint64_t* __restrict__ w3t,
                                              uint64_t* __restrict__ w1b,
                                              float* __restrict__ sc3,
                                              float* __restrict__ bi3,
                                              float* __restrict__ sc1,
                                              float* __restrict__ bi1,
                                              int* __restrict__ ptb) {
    int bx  = blockIdx.x;
    int tid = threadIdx.x;

    if (bx < 1568) {                                  // ---- sign-pack x ----
        int gid = bx * 256 + tid;                     // 0..401407
        if (gid < 7296) {                             // top padded row: 32*57*4
            int b = gid / 228, r = gid % 228;
            xbp[((size_t)(b * PH) * PH + (r >> 2)) * 4 + (r & 3)] = 0ull;
        } else if (gid < 14464) {                     // left padded col rows 1..56
            int i = gid - 7296;
            int b = i / 224, r = i % 224;
            xbp[((size_t)(b * PH + (r >> 2) + 1) * PH) * 4 + (r & 3)] = 0ull;
        }
        const int NP = BB * HH * WW;
        int pix = gid % NP;
        int cg  = gid / NP;                           // 0..3
        int w = pix % WW;
        int h = (pix / WW) % HH;
        int b = pix / (HH * WW);
        const float* xp = x + ((size_t)(b * CC1 + cg * 64)) * (HH * WW) + h * WW + w;
        uint64_t bits = 0;
        #pragma unroll 8
        for (int c = 0; c < 64; ++c) {
            bits |= (uint64_t)(xp[(size_t)c * (HH * WW)] >= 0.0f) << c;
        }
        xbp[((size_t)((b * PH + h + 1) * PH) + w + 1) * 4 + cg] = bits;
    } else if (bx < 1604) {                           // ---- pack w3 + shfl pad-corr ----
        int id = (bx - 1568) * 256 + tid;             // 0..9215
        int k   = id % 4;
        int tap = (id / 4) % 9;
        int oc  = id / 36;
        const float* wp = w3 + (size_t)oc * 2304 + (size_t)(k * 64) * 9 + tap;
        uint64_t bits = 0;
        #pragma unroll 8
        for (int c = 0; c < 64; ++c) {
            bits |= (uint64_t)(wp[c * 9] >= 0.0f) << c;
        }
        w3t[((size_t)tap * CC1 + oc) * 4 + k] = bits;
        int pc = popc64(bits);
        pc += __shfl_xor(pc, 1);
        pc += __shfl_xor(pc, 2);                      // all 4 lanes: Σ_k popc
        if (k == 0) {
            int tt = -1;                              // taps {0,1,2,3,6} -> slots 0..4
            if (tap <= 3) tt = tap;
            else if (tap == 6) tt = 4;
            if (tt >= 0) ptb[tt * 256 + oc] = 256 - 2 * pc;
        }
    } else {                                          // ---- pack w1 + BN folds ----
        int id = (bx - 1604) * 256 + tid;             // 0..2047
        int k  = id % 4;
        int oc = id / 4;
        const float* wp = w1 + (size_t)oc * 256 + k * 64;
        uint64_t bits = 0;
        #pragma unroll 8
        for (int c = 0; c < 64; ++c) {
            bits |= (uint64_t)(wp[c] >= 0.0f) << c;
        }
        w1b[(size_t)oc * 4 + k] = bits;
        if (k == 0) {
            float s1 = g1[oc] / sqrtf(v1[oc] + EPSV);
            sc1[oc] = s1;
            bi1[oc] = b1[oc] - m1[oc] * s1;
            if (oc < CC1) {
                float s3 = g3[oc] / sqrtf(v3[oc] + EPSV);
                sc3[oc] = s3;
                bi3[oc] = b3[oc] - m3[oc] * s3;
            }
        }
    }
}

// ---------- 3x3 stride-2 binary conv + BN + avgpool shortcut + byte sign-pack ----------
// R11 body + full kh unroll (single variable): hoist/interleave all 36 tap loads.
__global__ __launch_bounds__(256, 4) void k_conv3(const float* __restrict__ x,
                                                  const uint64_t* __restrict__ xbp,
                                                  const uint64_t* __restrict__ w3t,
                                                  const float* __restrict__ sc3,
                                                  const float* __restrict__ bi3,
                                                  const int* __restrict__ ptb,
                                                  unsigned short* __restrict__ hbuf,
                                                  uint8_t* __restrict__ hbits8) {
    int loc = blockIdx.x * 256 + threadIdx.x;         // 25088
    int p  = loc % NPIX;
    int ow = p % OWW;
    int oh = p / OWW;
    int b  = loc / NPIX;
    int ocg = blockIdx.y;                             // 0..31, 8 oc each (block-uniform)

    int tot[8] = {0,0,0,0,0,0,0,0};
    #pragma unroll
    for (int kh = 0; kh < 3; ++kh) {
        const uint64_t* rp = xbp + ((size_t)((b * PH + 2 * oh + kh) * PH) + 2 * ow) * 4;
        uint64_t t0[4], t1[4], t2[4];
        #pragma unroll
        for (int k = 0; k < 4; ++k) { t0[k] = rp[k]; t1[k] = rp[4 + k]; t2[k] = rp[8 + k]; }
        const uint64_t* wrow = w3t + ((size_t)(kh * 3) * CC1 + ocg * 8) * 4;
        #pragma unroll
        for (int o = 0; o < 8; ++o) {
            const uint64_t* w0  = wrow + (size_t)o * 4;
            const uint64_t* w1p = w0 + (size_t)CC1 * 4;
            const uint64_t* w2p = w0 + (size_t)CC1 * 8;
            int s = tot[o];
            #pragma unroll
            for (int k = 0; k < 4; ++k) s += popc64(t0[k] ^ w0[k]);
            #pragma unroll
            for (int k = 0; k < 4; ++k) s += popc64(t1[k] ^ w1p[k]);
            #pragma unroll
            for (int k = 0; k < 4; ++k) s += popc64(t2[k] ^ w2p[k]);
            tot[o] = s;
        }
    }

    bool top  = (oh == 0);
    bool left = (ow == 0);
    unsigned int hb = 0;
    #pragma unroll
    for (int o = 0; o < 8; ++o) {
        int oc = ocg * 8 + o;
        int corr = 0;
        if (top)  corr += ptb[oc] + ptb[256 + oc] + ptb[512 + oc];
        if (left) corr += ptb[oc] + ptb[768 + oc] + ptb[1024 + oc];
        if (top && left) corr -= ptb[oc];
        float y = (float)(2304 - 2 * tot[o] - corr);
        const float* px = x + ((size_t)(b * CC1 + oc)) * (HH * WW) + (2 * oh) * WW + 2 * ow;
        float2 r0 = *(const float2*)(px);
        float2 r1 = *(const float2*)(px + WW);
        float pool = 0.25f * (r0.x + r0.y + r1.x + r1.y);
        float hv = y * sc3[oc] + bi3[oc] + pool;
        hbuf[((size_t)(b * CC1 + oc)) * NPIX + p] = f2bf(hv);
        hb |= (unsigned int)(hv >= 0.0f) << o;
    }
    // each (pixel, ocg) owns a distinct byte: no atomics, no pre-zero.
    hbits8[(size_t)loc * 32 + (ocg >> 3) * 8 + (ocg & 7)] = (uint8_t)hb;
}

// ---------- 1x1 binary conv + BN + concat(h,h) shortcut (exact R10/R11) ----------
__global__ __launch_bounds__(256, 4) void k_conv1(const uint64_t* __restrict__ hbits,
                                                  const uint64_t* __restrict__ w1b,
                                                  const unsigned short* __restrict__ hbuf,
                                                  const float* __restrict__ sc1,
                                                  const float* __restrict__ bi1,
                                                  float* __restrict__ out) {
    int loc = blockIdx.x * 256 + threadIdx.x;         // 25088
    int p = loc % NPIX;
    int b = loc / NPIX;
    int ocg = blockIdx.y;                             // 0..31, 8 channel-pairs (block-uniform)

    uint64_t hw[4];
    const uint64_t* hp = hbits + (size_t)loc * 4;
    #pragma unroll
    for (int k = 0; k < 4; ++k) hw[k] = hp[k];

    #pragma unroll
    for (int o = 0; o < 8; ++o) {
        int oc  = ocg * 8 + o;          // 0..255
        int oc2 = oc + CC1;             // 256..511
        const uint64_t* wa = w1b + (size_t)oc  * 4;
        const uint64_t* wb = w1b + (size_t)oc2 * 4;
        int pa = 0, pb = 0;
        #pragma unroll
        for (int k = 0; k < 4; ++k) pa += popc64(hw[k] ^ wa[k]);
        #pragma unroll
        for (int k = 0; k < 4; ++k) pb += popc64(hw[k] ^ wb[k]);
        float hc = bf2f(hbuf[((size_t)(b * CC1 + oc)) * NPIX + p]);
        float za = (float)(256 - 2 * pa) * sc1[oc]  + bi1[oc]  + hc;
        float zb = (float)(256 - 2 * pb) * sc1[oc2] + bi1[oc2] + hc;
        out[((size_t)(b * CC2 + oc))  * NPIX + p] = za;
        out[((size_t)(b * CC2 + oc2)) * NPIX + p] = zb;
    }
}

extern "C" void kernel_launch(void* const* d_in, const int* in_sizes, int n_in,
                              void* d_out, int out_size, void* d_ws, size_t ws_size,
                              hipStream_t stream) {
    const float* x  = (const float*)d_in[0];
    const float* w3 = (const float*)d_in[1];
    const float* g3 = (const float*)d_in[2];
    const float* b3 = (const float*)d_in[3];
    const float* m3 = (const float*)d_in[4];
    const float* v3 = (const float*)d_in[5];
    const float* w1 = (const float*)d_in[6];
    const float* g1 = (const float*)d_in[7];
    const float* b1 = (const float*)d_in[8];
    const float* m1 = (const float*)d_in[9];
    const float* v1 = (const float*)d_in[10];
    float* out = (float*)d_out;

    uint8_t* ws = (uint8_t*)d_ws;
    size_t off = 0;
    uint64_t* xbp   = (uint64_t*)(ws + off); off += (size_t)BB * PH * PH * 4 * 8;   // 3,326,976
    uint64_t* hbits = (uint64_t*)(ws + off); off += (size_t)BB * NPIX * 4 * 8;      //   802,816
    uint64_t* w3t   = (uint64_t*)(ws + off); off += (size_t)9 * CC1 * 4 * 8;        //    73,728
    uint64_t* w1b   = (uint64_t*)(ws + off); off += (size_t)CC2 * 4 * 8;            //    16,384
    float* sc3 = (float*)(ws + off); off += CC1 * 4;
    float* bi3 = (float*)(ws + off); off += CC1 * 4;
    float* sc1 = (float*)(ws + off); off += CC2 * 4;
    float* bi1 = (float*)(ws + off); off += CC2 * 4;
    int* ptb   = (int*)(ws + off);   off += 5 * CC1 * 4;
    unsigned short* hbuf16 = (unsigned short*)(ws + off); off += (size_t)BB * CC1 * NPIX * 2; // 12,845,056

    k_binx <<<dim3(1612), 256, 0, stream>>>(x, w3, w1, g3, b3, m3, v3, g1, b1, m1, v1,
                                            xbp, w3t, w1b, sc3, bi3, sc1, bi1, ptb);
    k_conv3<<<dim3(98, 32), 256, 0, stream>>>(x, xbp, w3t, sc3, bi3, ptb,
                                              hbuf16, (uint8_t*)hbits);
    k_conv1<<<dim3(98, 32), 256, 0, stream>>>(hbits, w1b, hbuf16, sc1, bi1, out);
}

// Round 14
// 75.897 us; speedup vs baseline: 1.4991x; 1.4991x over previous
//
#include <hip/hip_runtime.h>
#include <stdint.h>

#define BB   32
#define CC1  256
#define HH   56
#define WW   56
#define PH   57          // padded (top/left zero row+col)
#define OHH  28
#define OWW  28
#define NPIX (OHH*OWW)   // 784
#define CC2  512
#define EPSV 1e-5f

static __device__ __forceinline__ int popc64(uint64_t v) {
    return __builtin_popcountll(v);
}
static __device__ __forceinline__ unsigned short f2bf(float f) {
    uint32_t u = __float_as_uint(f);
    u += 0x7FFFu + ((u >> 16) & 1u);          // RNE
    return (unsigned short)(u >> 16);
}
static __device__ __forceinline__ float bf2f(unsigned short u) {
    return __uint_as_float(((uint32_t)u) << 16);
}

// ---------- binx + ALL weight prep in one dispatch (exact R11 winner) ----------
__global__ __launch_bounds__(256) void k_binx(const float* __restrict__ x,
                                              const float* __restrict__ w3,
                                              const float* __restrict__ w1,
                                              const float* __restrict__ g3,
                                              const float* __restrict__ b3,
                                              const float* __restrict__ m3,
                                              const float* __restrict__ v3,
                                              const float* __restrict__ g1,
                                              const float* __restrict__ b1,
                                              const float* __restrict__ m1,
                                              const float* __restrict__ v1,
                                              uint64_t* __restrict__ xbp,
                                              uint64_t* __restrict__ w3t,
                                              uint64_t* __restrict__ w1b,
                                              float* __restrict__ sc3,
                                              float* __restrict__ bi3,
                                              float* __restrict__ sc1,
                                              float* __restrict__ bi1,
                                              int* __restrict__ ptb) {
    int bx  = blockIdx.x;
    int tid = threadIdx.x;

    if (bx < 1568) {                                  // ---- sign-pack x ----
        int gid = bx * 256 + tid;                     // 0..401407
        if (gid < 7296) {                             // top padded row: 32*57*4
            int b = gid / 228, r = gid % 228;
            xbp[((size_t)(b * PH) * PH + (r >> 2)) * 4 + (r & 3)] = 0ull;
        } else if (gid < 14464) {                     // left padded col rows 1..56
            int i = gid - 7296;
            int b = i / 224, r = i % 224;
            xbp[((size_t)(b * PH + (r >> 2) + 1) * PH) * 4 + (r & 3)] = 0ull;
        }
        const int NP = BB * HH * WW;
        int pix = gid % NP;
        int cg  = gid / NP;                           // 0..3
        int w = pix % WW;
        int h = (pix / WW) % HH;
        int b = pix / (HH * WW);
        const float* xp = x + ((size_t)(b * CC1 + cg * 64)) * (HH * WW) + h * WW + w;
        uint64_t bits = 0;
        #pragma unroll 8
        for (int c = 0; c < 64; ++c) {
            bits |= (uint64_t)(xp[(size_t)c * (HH * WW)] >= 0.0f) << c;
        }
        xbp[((size_t)((b * PH + h + 1) * PH) + w + 1) * 4 + cg] = bits;
    } else if (bx < 1604) {                           // ---- pack w3 + shfl pad-corr ----
        int id = (bx - 1568) * 256 + tid;             // 0..9215
        int k   = id % 4;
        int tap = (id / 4) % 9;
        int oc  = id / 36;
        const float* wp = w3 + (size_t)oc * 2304 + (size_t)(k * 64) * 9 + tap;
        uint64_t bits = 0;
        #pragma unroll 8
        for (int c = 0; c < 64; ++c) {
            bits |= (uint64_t)(wp[c * 9] >= 0.0f) << c;
        }
        w3t[((size_t)tap * CC1 + oc) * 4 + k] = bits;
        int pc = popc64(bits);
        pc += __shfl_xor(pc, 1);
        pc += __shfl_xor(pc, 2);                      // all 4 lanes: Σ_k popc
        if (k == 0) {
            int tt = -1;                              // taps {0,1,2,3,6} -> slots 0..4
            if (tap <= 3) tt = tap;
            else if (tap == 6) tt = 4;
            if (tt >= 0) ptb[tt * 256 + oc] = 256 - 2 * pc;
        }
    } else {                                          // ---- pack w1 + BN folds ----
        int id = (bx - 1604) * 256 + tid;             // 0..2047
        int k  = id % 4;
        int oc = id / 4;
        const float* wp = w1 + (size_t)oc * 256 + k * 64;
        uint64_t bits = 0;
        #pragma unroll 8
        for (int c = 0; c < 64; ++c) {
            bits |= (uint64_t)(wp[c] >= 0.0f) << c;
        }
        w1b[(size_t)oc * 4 + k] = bits;
        if (k == 0) {
            float s1 = g1[oc] / sqrtf(v1[oc] + EPSV);
            sc1[oc] = s1;
            bi1[oc] = b1[oc] - m1[oc] * s1;
            if (oc < CC1) {
                float s3 = g3[oc] / sqrtf(v3[oc] + EPSV);
                sc3[oc] = s3;
                bi3[oc] = b3[oc] - m3[oc] * s3;
            }
        }
    }
}

// ---------- 3x3 stride-2 binary conv + BN + avgpool shortcut + byte sign-pack ----------
// EXACT R11 body (rolled kh loop, 8 oc/thread — proven local optimum).
__global__ __launch_bounds__(256, 4) void k_conv3(const float* __restrict__ x,
                                                  const uint64_t* __restrict__ xbp,
                                                  const uint64_t* __restrict__ w3t,
                                                  const float* __restrict__ sc3,
                                                  const float* __restrict__ bi3,
                                                  const int* __restrict__ ptb,
                                                  unsigned short* __restrict__ hbuf,
                                                  uint8_t* __restrict__ hbits8) {
    int loc = blockIdx.x * 256 + threadIdx.x;         // 25088
    int p  = loc % NPIX;
    int ow = p % OWW;
    int oh = p / OWW;
    int b  = loc / NPIX;
    int ocg = blockIdx.y;                             // 0..31, 8 oc each (block-uniform)

    int tot[8] = {0,0,0,0,0,0,0,0};
    for (int kh = 0; kh < 3; ++kh) {
        const uint64_t* rp = xbp + ((size_t)((b * PH + 2 * oh + kh) * PH) + 2 * ow) * 4;
        uint64_t t0[4], t1[4], t2[4];
        #pragma unroll
        for (int k = 0; k < 4; ++k) { t0[k] = rp[k]; t1[k] = rp[4 + k]; t2[k] = rp[8 + k]; }
        const uint64_t* wrow = w3t + ((size_t)(kh * 3) * CC1 + ocg * 8) * 4;
        #pragma unroll
        for (int o = 0; o < 8; ++o) {
            const uint64_t* w0  = wrow + (size_t)o * 4;
            const uint64_t* w1p = w0 + (size_t)CC1 * 4;
            const uint64_t* w2p = w0 + (size_t)CC1 * 8;
            int s = tot[o];
            #pragma unroll
            for (int k = 0; k < 4; ++k) s += popc64(t0[k] ^ w0[k]);
            #pragma unroll
            for (int k = 0; k < 4; ++k) s += popc64(t1[k] ^ w1p[k]);
            #pragma unroll
            for (int k = 0; k < 4; ++k) s += popc64(t2[k] ^ w2p[k]);
            tot[o] = s;
        }
    }

    bool top  = (oh == 0);
    bool left = (ow == 0);
    unsigned int hb = 0;
    #pragma unroll
    for (int o = 0; o < 8; ++o) {
        int oc = ocg * 8 + o;
        int corr = 0;
        if (top)  corr += ptb[oc] + ptb[256 + oc] + ptb[512 + oc];
        if (left) corr += ptb[oc] + ptb[768 + oc] + ptb[1024 + oc];
        if (top && left) corr -= ptb[oc];
        float y = (float)(2304 - 2 * tot[o] - corr);
        const float* px = x + ((size_t)(b * CC1 + oc)) * (HH * WW) + (2 * oh) * WW + 2 * ow;
        float2 r0 = *(const float2*)(px);
        float2 r1 = *(const float2*)(px + WW);
        float pool = 0.25f * (r0.x + r0.y + r1.x + r1.y);
        float hv = y * sc3[oc] + bi3[oc] + pool;
        hbuf[((size_t)(b * CC1 + oc)) * NPIX + p] = f2bf(hv);
        hb |= (unsigned int)(hv >= 0.0f) << o;
    }
    // each (pixel, ocg) owns a distinct byte: no atomics, no pre-zero.
    hbits8[(size_t)loc * 32 + (ocg >> 3) * 8 + (ocg & 7)] = (uint8_t)hb;
}

// ---------- 1x1 binary conv + BN + concat(h,h) shortcut ----------
// R11 body + nontemporal out stores (out is write-once; keep L2/L3 for x/hbuf).
__global__ __launch_bounds__(256, 4) void k_conv1(const uint64_t* __restrict__ hbits,
                                                  const uint64_t* __restrict__ w1b,
                                                  const unsigned short* __restrict__ hbuf,
                                                  const float* __restrict__ sc1,
                                                  const float* __restrict__ bi1,
                                                  float* __restrict__ out) {
    int loc = blockIdx.x * 256 + threadIdx.x;         // 25088
    int p = loc % NPIX;
    int b = loc / NPIX;
    int ocg = blockIdx.y;                             // 0..31, 8 channel-pairs (block-uniform)

    uint64_t hw[4];
    const uint64_t* hp = hbits + (size_t)loc * 4;
    #pragma unroll
    for (int k = 0; k < 4; ++k) hw[k] = hp[k];

    #pragma unroll
    for (int o = 0; o < 8; ++o) {
        int oc  = ocg * 8 + o;          // 0..255
        int oc2 = oc + CC1;             // 256..511
        const uint64_t* wa = w1b + (size_t)oc  * 4;
        const uint64_t* wb = w1b + (size_t)oc2 * 4;
        int pa = 0, pb = 0;
        #pragma unroll
        for (int k = 0; k < 4; ++k) pa += popc64(hw[k] ^ wa[k]);
        #pragma unroll
        for (int k = 0; k < 4; ++k) pb += popc64(hw[k] ^ wb[k]);
        float hc = bf2f(hbuf[((size_t)(b * CC1 + oc)) * NPIX + p]);
        float za = (float)(256 - 2 * pa) * sc1[oc]  + bi1[oc]  + hc;
        float zb = (float)(256 - 2 * pb) * sc1[oc2] + bi1[oc2] + hc;
        __builtin_nontemporal_store(za, out + ((size_t)(b * CC2 + oc))  * NPIX + p);
        __builtin_nontemporal_store(zb, out + ((size_t)(b * CC2 + oc2)) * NPIX + p);
    }
}

extern "C" void kernel_launch(void* const* d_in, const int* in_sizes, int n_in,
                              void* d_out, int out_size, void* d_ws, size_t ws_size,
                              hipStream_t stream) {
    const float* x  = (const float*)d_in[0];
    const float* w3 = (const float*)d_in[1];
    const float* g3 = (const float*)d_in[2];
    const float* b3 = (const float*)d_in[3];
    const float* m3 = (const float*)d_in[4];
    const float* v3 = (const float*)d_in[5];
    const float* w1 = (const float*)d_in[6];
    const float* g1 = (const float*)d_in[7];
    const float* b1 = (const float*)d_in[8];
    const float* m1 = (const float*)d_in[9];
    const float* v1 = (const float*)d_in[10];
    float* out = (float*)d_out;

    uint8_t* ws = (uint8_t*)d_ws;
    size_t off = 0;
    uint64_t* xbp   = (uint64_t*)(ws + off); off += (size_t)BB * PH * PH * 4 * 8;   // 3,326,976
    uint64_t* hbits = (uint64_t*)(ws + off); off += (size_t)BB * NPIX * 4 * 8;      //   802,816
    uint64_t* w3t   = (uint64_t*)(ws + off); off += (size_t)9 * CC1 * 4 * 8;        //    73,728
    uint64_t* w1b   = (uint64_t*)(ws + off); off += (size_t)CC2 * 4 * 8;            //    16,384
    float* sc3 = (float*)(ws + off); off += CC1 * 4;
    float* bi3 = (float*)(ws + off); off += CC1 * 4;
    float* sc1 = (float*)(ws + off); off += CC2 * 4;
    float* bi1 = (float*)(ws + off); off += CC2 * 4;
    int* ptb   = (int*)(ws + off);   off += 5 * CC1 * 4;
    unsigned short* hbuf16 = (unsigned short*)(ws + off); off += (size_t)BB * CC1 * NPIX * 2; // 12,845,056

    k_binx <<<dim3(1612), 256, 0, stream>>>(x, w3, w1, g3, b3, m3, v3, g1, b1, m1, v1,
                                            xbp, w3t, w1b, sc3, bi3, sc1, bi1, ptb);
    k_conv3<<<dim3(98, 32), 256, 0, stream>>>(x, xbp, w3t, sc3, bi3, ptb,
                                              hbuf16, (uint8_t*)hbits);
    k_conv1<<<dim3(98, 32), 256, 0, stream>>>(hbits, w1b, hbuf16, sc1, bi1, out);
}